// Round 3
// baseline (251.123 us; speedup 1.0000x reference)
//
#include <hip/hip_runtime.h>
#include <hip/hip_fp16.h>

// VariationalGCNEncoder: N=50000 nodes, E=600000 edges, 128->128(relu)->2x64
// out = mu (50000x64) then logstd (50000x64), flat concat.
//
// R1: hierarchical scan. R2: float4 gather, dis pre-scaling. R3: LDS GEMM.
// R4: fp16 aggregation operand. R5: MFMA fp16 GEMM. R6: W^T prep + swapped
// MFMA operands + grid-stride + quarter-wave aggregate (222us).
// R7: plane-major SPATIAL chunking (chunk=bid&3, XCD pinning) -> REGRESSED
//     (246us): workgroup->XCD mapping not stable; all 4 chunks live at once
//     so the working set never shrank; paid 4x CSR overhead for nothing.
// R8: fused agg2+gemm2 -> REGRESSED (239us): grid 782 x 51KB LDS -> 16%
//     occupancy, latency-bound gather starved of parallelism. Unfused.
// R9 (this round): TEMPORAL chunking. Same plane-major [4][N][32] layout and
//     aggregate kernel as R7, but chunk = bid / 3125 (outer dimension):
//     blocks dispatch chunk-by-chunk, so at any instant the live gather
//     working set is one 3.2 MB plane -> fits replicated in every XCD's 4 MB
//     L2 (no XCD-assignment assumption needed). Split gemm2 (R7 form),
//     prep_wt also zeros counts+fillcnt (drops memset dispatch).

#define N_NODES 50000
#define N_EDGES 600000
#define MU_SIZE (N_NODES * 64)
#define SCAN_BLOCKS 200
#define SCAN_CHUNK 250  // SCAN_BLOCKS * SCAN_CHUNK == N_NODES
#define WT_S 136        // LDS row stride (halves), 272B: 16B-aligned rows
#define PLANE (N_NODES * 32)  // halves per feature-plane (3.2 MB)
#define NB_AGG 3125           // node-blocks per chunk (16 nodes/block)

typedef _Float16 half8 __attribute__((ext_vector_type(8)));
typedef _Float16 half4 __attribute__((ext_vector_type(4)));
typedef float floatx4 __attribute__((ext_vector_type(4)));

__global__ __launch_bounds__(256) void count_kernel(const int* __restrict__ col,
                                                    int* __restrict__ counts, int e) {
  int i = blockIdx.x * 256 + threadIdx.x;
  if (i < e) atomicAdd(&counts[col[i]], 1);
}

// Per-block partial sums of counts (250 elems/block) + dis = rsqrt(deg+1)
__global__ __launch_bounds__(256) void blocksum_dis_kernel(const int* __restrict__ counts,
                                                           float* __restrict__ dis,
                                                           int* __restrict__ blocksums) {
  __shared__ int red[4];
  int b = blockIdx.x, t = threadIdx.x;
  int i = b * SCAN_CHUNK + t;
  int c = 0;
  if (t < SCAN_CHUNK) {
    c = counts[i];
    dis[i] = rsqrtf((float)(c + 1));  // +1 self-loop => deg >= 1 always
  }
  int s = c;
#pragma unroll
  for (int off = 32; off > 0; off >>= 1) s += __shfl_down(s, off, 64);
  if ((t & 63) == 0) red[t >> 6] = s;
  __syncthreads();
  if (t == 0) blocksums[b] = red[0] + red[1] + red[2] + red[3];
}

// Each block: scan the 200 blocksums in LDS for its exclusive base, then
// scan its own 250 counts and write exclusive offsets.
__global__ __launch_bounds__(256) void offsets_kernel(const int* __restrict__ counts,
                                                      const int* __restrict__ blocksums,
                                                      int* __restrict__ offsets) {
  __shared__ int sb[256];
  __shared__ int loc[256];
  int b = blockIdx.x, t = threadIdx.x;
  sb[t] = (t < SCAN_BLOCKS) ? blocksums[t] : 0;
  __syncthreads();
#pragma unroll
  for (int off = 1; off < 256; off <<= 1) {
    int v = (t >= off) ? sb[t - off] : 0;
    __syncthreads();
    sb[t] += v;
    __syncthreads();
  }
  int base = (b == 0) ? 0 : sb[b - 1];
  int i = b * SCAN_CHUNK + t;
  int c = (t < SCAN_CHUNK) ? counts[i] : 0;
  loc[t] = c;
  __syncthreads();
#pragma unroll
  for (int off = 1; off < 256; off <<= 1) {
    int v = (t >= off) ? loc[t - off] : 0;
    __syncthreads();
    loc[t] += v;
    __syncthreads();
  }
  if (t < SCAN_CHUNK) offsets[i] = base + loc[t] - c;  // exclusive
  if (b == SCAN_BLOCKS - 1 && t == SCAN_CHUNK - 1) offsets[N_NODES] = base + loc[t];
}

__global__ __launch_bounds__(256) void fill_kernel(const int* __restrict__ row,
                                                   const int* __restrict__ col,
                                                   const int* __restrict__ offsets,
                                                   int* __restrict__ fillcnt,
                                                   int* __restrict__ srcidx, int e) {
  int i = blockIdx.x * 256 + threadIdx.x;
  if (i < e) {
    int c = col[i];
    int pos = offsets[c] + atomicAdd(&fillcnt[c], 1);
    srcidx[pos] = row[i];
  }
}

// Build fp16 transposed weights in global once; also zero counts+fillcnt
// (contiguous 2*N ints) so the memset dispatch is dropped.
// W1T[n][k] = fp16(W1[k][n]); W2T[n][k] = fp16(n<64 ? Wmu[k][n] : Wls[k][n-64])
__global__ __launch_bounds__(256) void prep_wt_kernel(const float* __restrict__ W1,
                                                      const float* __restrict__ Wmu,
                                                      const float* __restrict__ Wls,
                                                      _Float16* __restrict__ W1T,
                                                      _Float16* __restrict__ W2T,
                                                      int* __restrict__ zero2n) {
  int idx = blockIdx.x * 256 + threadIdx.x;  // grid 128 -> 32768
  for (int z = idx; z < 2 * N_NODES; z += 32768) zero2n[z] = 0;
  int e = idx & 16383;
  int n = e >> 7, k = e & 127;
  if (idx < 16384) {
    W1T[e] = (_Float16)W1[k * 128 + n];
  } else {
    float w = (n < 64) ? Wmu[k * 64 + n] : Wls[k * 64 + (n - 64)];
    W2T[e] = (_Float16)w;
  }
}

// MFMA GEMM, M=50000 nodes, K=128, 128 output feats. Block = 4 waves;
// each wave-iteration covers 16 nodes x 128 feats.
// A = W^T tile (16 feats x 32 k, from LDS), B = X^T (32 k x 16 nodes).
// D: lane(q,m) -> node m, feats 16f+4q..+3.
// SPLIT=false (gemm1): B from fp32 X (cvt), out fp16 plane-major
//   Yh[p][node][c] = dis[node]*(X@W1), p = feat>>5, c = feat&31.
// SPLIT=true  (gemm2): B fragments from plane-major fp16 Xh (half8 at plane c,
//   node row, cols 8q..8q+7), out fp32 mu/logstd split + bias.
template <bool SPLIT>
__global__ __launch_bounds__(256) void gemm_mfma_kernel(const float* __restrict__ X,
                                                        const _Float16* __restrict__ Xh,
                                                        const _Float16* __restrict__ WT,
                                                        const float* __restrict__ dis,
                                                        const float* __restrict__ ba,
                                                        const float* __restrict__ bb,
                                                        _Float16* __restrict__ Yh,
                                                        float* __restrict__ Yf) {
  __shared__ _Float16 WL[128 * WT_S];  // 34 KB

  int t = threadIdx.x;
  // stage W^T: coalesced b128 global reads, conflict-free LDS writes
  for (int idx = t; idx < 128 * 16; idx += 256) {
    int n = idx >> 4, kk = (idx & 15) * 8;
    *(half8*)&WL[n * WT_S + kk] = *(const half8*)&WT[n * 128 + kk];
  }
  __syncthreads();

  int wid = t >> 6, lane = t & 63;
  int q = lane >> 4, m = lane & 15;
  const int ngroups = (N_NODES + 63) / 64;  // 782

  for (int g64 = blockIdx.x; g64 < ngroups; g64 += gridDim.x) {
    int node = g64 * 64 + wid * 16 + m;
    size_t nr = (size_t)min(node, N_NODES - 1);
    bool valid = node < N_NODES;

    // B fragments: lane (q,m) holds X[node][32c + 8q + j], j=0..7
    half8 xfrag[4];
    if (!SPLIT) {
#pragma unroll
      for (int c = 0; c < 4; ++c) {
        const float* ap = &X[nr * 128 + 32 * c + 8 * q];
        float4 a0 = *(const float4*)ap;
        float4 a1 = *(const float4*)(ap + 4);
        half8 af = {(_Float16)a0.x, (_Float16)a0.y, (_Float16)a0.z, (_Float16)a0.w,
                    (_Float16)a1.x, (_Float16)a1.y, (_Float16)a1.z, (_Float16)a1.w};
        xfrag[c] = af;
      }
    } else {
#pragma unroll
      for (int c = 0; c < 4; ++c) {
        // plane-major: plane c holds feats 32c..32c+31
        xfrag[c] = *(const half8*)&Xh[(size_t)c * PLANE + nr * 32 + 8 * q];
      }
    }
    float dnode = SPLIT ? 0.f : dis[nr];

#pragma unroll
    for (int f = 0; f < 8; ++f) {  // feat tile: feats 16f..16f+15
      floatx4 acc = {0.f, 0.f, 0.f, 0.f};
#pragma unroll
      for (int c = 0; c < 4; ++c) {
        half8 wfrag = *(const half8*)&WL[(16 * f + m) * WT_S + 32 * c + 8 * q];
        acc = __builtin_amdgcn_mfma_f32_16x16x32_f16(wfrag, xfrag[c], acc, 0, 0, 0);
      }
      int fbase = 16 * f + 4 * q;  // 4 consecutive feats for this lane
      if (!SPLIT) {
        if (valid) {
          half4 o = {(_Float16)(acc[0] * dnode), (_Float16)(acc[1] * dnode),
                     (_Float16)(acc[2] * dnode), (_Float16)(acc[3] * dnode)};
          int p = fbase >> 5, c0 = fbase & 31;  // plane, col (c0 in {0,4,...,28})
          *(half4*)&Yh[(size_t)p * PLANE + (size_t)node * 32 + c0] = o;
        }
      } else {
        // f<4 -> mu cols (fbase<64), f>=4 -> logstd (wave-uniform branch)
        float4 bias = (f < 4) ? *(const float4*)&ba[fbase]
                              : *(const float4*)&bb[fbase - 64];
        float4 o = make_float4(acc[0] + bias.x, acc[1] + bias.y, acc[2] + bias.z,
                               acc[3] + bias.w);
        if (valid) {
          if (f < 4)
            *(float4*)&Yf[(size_t)node * 64 + fbase] = o;
          else
            *(float4*)&Yf[MU_SIZE + (size_t)node * 64 + (fbase - 64)] = o;
        }
      }
    }
  }
}

// TEMPORALLY feature-chunked aggregation over plane-major fp16 H (pre-scaled
// by dis). chunk p = bid / NB_AGG: blocks are dispatched chunk-by-chunk, so
// the live gather working set at any instant is ~one 3.2 MB plane, which fits
// (replicated) in each XCD's 4 MB L2 regardless of block->XCD assignment.
// Quarter-wave (16 lanes x __half2) per node; gather loop unroll-8.
// BIAS_RELU=true:  out[p][i] = fp16( di * relu(di*(sum Hs[r] + Hs[i]) + b) )
// BIAS_RELU=false: out[p][i] = fp16( di * (sum Hs[r] + Hs[i]) )
template <bool BIAS_RELU>
__global__ __launch_bounds__(256) void aggregate_kernel(const __half* __restrict__ Hs,
                                                        const int* __restrict__ offsets,
                                                        const int* __restrict__ srcidx,
                                                        const float* __restrict__ dis,
                                                        const float* __restrict__ bias,
                                                        __half* __restrict__ outH, int n) {
  int bid = blockIdx.x;
  int p = bid / NB_AGG;        // feature plane (outer -> temporal phases)
  int nb = bid - p * NB_AGG;   // node-block
  int wid = threadIdx.x >> 6, lane = threadIdx.x & 63;
  int q = lane >> 4, ql = lane & 15;
  int i = nb * 16 + wid * 4 + q;
  if (i >= n) return;
  const __half* plane = Hs + (size_t)p * PLANE;
  float di = dis[i];
  __half2 selfv = *(const __half2*)(plane + (size_t)i * 32 + 2 * ql);
  float ax = 0.f, ay = 0.f;
  int k = offsets[i], end = offsets[i + 1];
  for (; k + 7 < end; k += 8) {
    int r0 = srcidx[k], r1 = srcidx[k + 1], r2 = srcidx[k + 2], r3 = srcidx[k + 3];
    int r4 = srcidx[k + 4], r5 = srcidx[k + 5], r6 = srcidx[k + 6], r7 = srcidx[k + 7];
    __half2 v0 = *(const __half2*)(plane + (size_t)r0 * 32 + 2 * ql);
    __half2 v1 = *(const __half2*)(plane + (size_t)r1 * 32 + 2 * ql);
    __half2 v2 = *(const __half2*)(plane + (size_t)r2 * 32 + 2 * ql);
    __half2 v3 = *(const __half2*)(plane + (size_t)r3 * 32 + 2 * ql);
    __half2 v4 = *(const __half2*)(plane + (size_t)r4 * 32 + 2 * ql);
    __half2 v5 = *(const __half2*)(plane + (size_t)r5 * 32 + 2 * ql);
    __half2 v6 = *(const __half2*)(plane + (size_t)r6 * 32 + 2 * ql);
    __half2 v7 = *(const __half2*)(plane + (size_t)r7 * 32 + 2 * ql);
    float2 f0 = __half22float2(v0), f1 = __half22float2(v1);
    float2 f2 = __half22float2(v2), f3 = __half22float2(v3);
    float2 f4 = __half22float2(v4), f5 = __half22float2(v5);
    float2 f6 = __half22float2(v6), f7 = __half22float2(v7);
    ax += ((f0.x + f1.x) + (f2.x + f3.x)) + ((f4.x + f5.x) + (f6.x + f7.x));
    ay += ((f0.y + f1.y) + (f2.y + f3.y)) + ((f4.y + f5.y) + (f6.y + f7.y));
  }
  for (; k < end; ++k) {
    int r0 = srcidx[k];
    float2 f0 = __half22float2(*(const __half2*)(plane + (size_t)r0 * 32 + 2 * ql));
    ax += f0.x;
    ay += f0.y;
  }
  float2 sf = __half22float2(selfv);
  float sx = di * (ax + sf.x);
  float sy = di * (ay + sf.y);
  __half2 o;
  if (BIAS_RELU) {
    float2 b = *(const float2*)&bias[p * 32 + 2 * ql];
    o = __float22half2_rn(
        make_float2(di * fmaxf(sx + b.x, 0.f), di * fmaxf(sy + b.y, 0.f)));
  } else {
    o = __float22half2_rn(make_float2(sx, sy));
  }
  *(__half2*)(outH + (size_t)p * PLANE + (size_t)i * 32 + 2 * ql) = o;
}

extern "C" void kernel_launch(void* const* d_in, const int* in_sizes, int n_in,
                              void* d_out, int out_size, void* d_ws, size_t ws_size,
                              hipStream_t stream) {
  const float* x = (const float*)d_in[0];
  const int* ei = (const int*)d_in[1];  // [2][E] int32: row=src, col=dst
  const float* W1 = (const float*)d_in[2];
  const float* b1 = (const float*)d_in[3];
  const float* Wmu = (const float*)d_in[4];
  const float* bmu = (const float*)d_in[5];
  const float* Wls = (const float*)d_in[6];
  const float* bls = (const float*)d_in[7];
  float* out = (float*)d_out;

  const int* row = ei;
  const int* col = ei + N_EDGES;

  // workspace layout (~42 MB)
  __half* bufAh = (__half*)d_ws;               // 6.4M f16 (gemm1 out, agg1 in) [4][N][32]
  __half* bufBh = bufAh + 6400000;             // 6.4M f16 (agg1 out, agg2 in)  [4][N][32]
  __half* bufCh = bufBh + 6400000;             // 6.4M f16 (agg2 out, gemm2 in) [4][N][32]
  float* dis = (float*)(bufCh + 6400000);      // 50000 f32
  int* counts = (int*)(dis + N_NODES);         // 50000 i32
  int* fillcnt = counts + N_NODES;             // 50000 i32 (contiguous after counts)
  int* offsets = fillcnt + N_NODES;            // 50001 i32
  int* srcidx = offsets + N_NODES + 1;         // 600000 i32
  int* blocksums = srcidx + N_EDGES;           // 200 i32
  _Float16* W1T = (_Float16*)(blocksums + 256);  // 16384 f16
  _Float16* W2T = W1T + 16384;                   // 16384 f16

  prep_wt_kernel<<<128, 256, 0, stream>>>(W1, Wmu, Wls, W1T, W2T, counts);

  int eb = (N_EDGES + 255) / 256;
  count_kernel<<<eb, 256, 0, stream>>>(col, counts, N_EDGES);
  blocksum_dis_kernel<<<SCAN_BLOCKS, 256, 0, stream>>>(counts, dis, blocksums);
  offsets_kernel<<<SCAN_BLOCKS, 256, 0, stream>>>(counts, blocksums, offsets);
  fill_kernel<<<eb, 256, 0, stream>>>(row, col, offsets, fillcnt, srcidx, N_EDGES);

  gemm_mfma_kernel<false><<<512, 256, 0, stream>>>(x, nullptr, W1T, dis, nullptr, nullptr,
                                                   (_Float16*)bufAh, nullptr);
  aggregate_kernel<true><<<4 * NB_AGG, 256, 0, stream>>>(bufAh, offsets, srcidx, dis, b1,
                                                         bufBh, N_NODES);
  aggregate_kernel<false><<<4 * NB_AGG, 256, 0, stream>>>(bufBh, offsets, srcidx, dis,
                                                          nullptr, bufCh, N_NODES);
  gemm_mfma_kernel<true><<<512, 256, 0, stream>>>(nullptr, (const _Float16*)bufCh, W2T,
                                                  nullptr, bmu, bls, nullptr, out);
}

// Round 4
// 218.604 us; speedup vs baseline: 1.1488x; 1.1488x over previous
//
#include <hip/hip_runtime.h>
#include <hip/hip_fp16.h>

// VariationalGCNEncoder: N=50000 nodes, E=600000 edges, 128->128(relu)->2x64
// out = mu (50000x64) then logstd (50000x64), flat concat.
//
// R1: hierarchical scan. R2: float4 gather, dis pre-scaling. R3: LDS GEMM.
// R4: fp16 aggregation operand. R5: MFMA fp16 GEMM. R6: W^T prep + swapped
// MFMA operands + grid-stride + quarter-wave aggregate (222us).
// R7: spatial XCD chunking -> REGRESSED (246). R8: fused agg2+gemm2 ->
// REGRESSED (239, 16% occupancy). R9: temporal chunking -> REGRESSED (251):
// agg counters showed latency-bound (VALU 32%, HBM 21%, occ 65%), and per-XCD
// L2 replication defeats residency schemes. All reverted.
// R10 (this round): R6 row-major structure + PADDED CSR. Every adjacency
// list is padded to a multiple of 8 with dummy src = N_NODES pointing at a
// zero row (row N of bufA/bufB, zeroed in prep). The gather loop becomes a
// branch-free unroll-8 (8 rows x 16B/lane in flight, no serialized remainder
// loop -- the previous critical path: up to 7 dependent ~600ns gathers).
// prep also zeroes counts/fillcnt and prefills srcidx pads (no memset).

#define N_NODES 50000
#define N_EDGES 600000
#define MU_SIZE (N_NODES * 64)
#define SCAN_BLOCKS 200
#define SCAN_CHUNK 250  // SCAN_BLOCKS * SCAN_CHUNK == N_NODES
#define WT_S 136        // LDS row stride (halves), 272B: 16B-aligned rows
#define PAD_CAP 960000  // srcidx capacity: 600000 + 7*50000 = 950000 max

typedef _Float16 half8 __attribute__((ext_vector_type(8)));
typedef _Float16 half4 __attribute__((ext_vector_type(4)));
typedef float floatx4 __attribute__((ext_vector_type(4)));

union H8 { __half2 h2[4]; float4 f4; };

__global__ __launch_bounds__(256) void count_kernel(const int* __restrict__ col,
                                                    int* __restrict__ counts, int e) {
  int i = blockIdx.x * 256 + threadIdx.x;
  if (i < e) atomicAdd(&counts[col[i]], 1);
}

// Per-block partial sums of PADDED counts (250 elems/block) + dis = rsqrt(deg+1)
__global__ __launch_bounds__(256) void blocksum_dis_kernel(const int* __restrict__ counts,
                                                           float* __restrict__ dis,
                                                           int* __restrict__ blocksums) {
  __shared__ int red[4];
  int b = blockIdx.x, t = threadIdx.x;
  int i = b * SCAN_CHUNK + t;
  int dp = 0;
  if (t < SCAN_CHUNK) {
    int c = counts[i];
    dis[i] = rsqrtf((float)(c + 1));  // +1 self-loop => deg >= 1 always
    dp = (c + 7) & ~7;                // padded degree (multiple of 8)
  }
  int s = dp;
#pragma unroll
  for (int off = 32; off > 0; off >>= 1) s += __shfl_down(s, off, 64);
  if ((t & 63) == 0) red[t >> 6] = s;
  __syncthreads();
  if (t == 0) blocksums[b] = red[0] + red[1] + red[2] + red[3];
}

// Each block: scan the 200 blocksums in LDS for its exclusive base, then
// scan its own 250 PADDED counts and write exclusive offsets.
__global__ __launch_bounds__(256) void offsets_kernel(const int* __restrict__ counts,
                                                      const int* __restrict__ blocksums,
                                                      int* __restrict__ offsets) {
  __shared__ int sb[256];
  __shared__ int loc[256];
  int b = blockIdx.x, t = threadIdx.x;
  sb[t] = (t < SCAN_BLOCKS) ? blocksums[t] : 0;
  __syncthreads();
#pragma unroll
  for (int off = 1; off < 256; off <<= 1) {
    int v = (t >= off) ? sb[t - off] : 0;
    __syncthreads();
    sb[t] += v;
    __syncthreads();
  }
  int base = (b == 0) ? 0 : sb[b - 1];
  int i = b * SCAN_CHUNK + t;
  int dp = 0;
  if (t < SCAN_CHUNK) dp = (counts[i] + 7) & ~7;
  loc[t] = dp;
  __syncthreads();
#pragma unroll
  for (int off = 1; off < 256; off <<= 1) {
    int v = (t >= off) ? loc[t - off] : 0;
    __syncthreads();
    loc[t] += v;
    __syncthreads();
  }
  if (t < SCAN_CHUNK) offsets[i] = base + loc[t] - dp;  // exclusive
  if (b == SCAN_BLOCKS - 1 && t == SCAN_CHUNK - 1) offsets[N_NODES] = base + loc[t];
}

// Real edges fill the first deg slots of each node's padded segment; the pad
// slots keep the prep-written dummy src = N_NODES (zero row).
__global__ __launch_bounds__(256) void fill_kernel(const int* __restrict__ row,
                                                   const int* __restrict__ col,
                                                   const int* __restrict__ offsets,
                                                   int* __restrict__ fillcnt,
                                                   int* __restrict__ srcidx, int e) {
  int i = blockIdx.x * 256 + threadIdx.x;
  if (i < e) {
    int c = col[i];
    int pos = offsets[c] + atomicAdd(&fillcnt[c], 1);
    srcidx[pos] = row[i];
  }
}

// One-time prep: fp16 transposed weights; zero counts+fillcnt; prefill the
// whole srcidx array with the dummy src N_NODES; zero row N of bufA/bufB.
// W1T[n][k] = fp16(W1[k][n]); W2T[n][k] = fp16(n<64 ? Wmu[k][n] : Wls[k][n-64])
__global__ __launch_bounds__(256) void prep_kernel(const float* __restrict__ W1,
                                                   const float* __restrict__ Wmu,
                                                   const float* __restrict__ Wls,
                                                   _Float16* __restrict__ W1T,
                                                   _Float16* __restrict__ W2T,
                                                   int* __restrict__ zero2n,
                                                   int* __restrict__ srcidx,
                                                   __half* __restrict__ zrowA,
                                                   __half* __restrict__ zrowB) {
  int idx = blockIdx.x * 256 + threadIdx.x;  // grid 128 -> 32768
  for (int z = idx; z < 2 * N_NODES; z += 32768) zero2n[z] = 0;
  for (int z = idx; z < PAD_CAP; z += 32768) srcidx[z] = N_NODES;
  if (idx < 128) {
    zrowA[idx] = __float2half(0.f);
    zrowB[idx] = __float2half(0.f);
  }
  int e = idx & 16383;
  int n = e >> 7, k = e & 127;
  if (idx < 16384) {
    W1T[e] = (_Float16)W1[k * 128 + n];
  } else {
    float w = (n < 64) ? Wmu[k * 64 + n] : Wls[k * 64 + (n - 64)];
    W2T[e] = (_Float16)w;
  }
}

// MFMA GEMM, M=50000 nodes, K=128, 128 output feats. Block = 4 waves;
// each wave-iteration covers 16 nodes x 128 feats.
// A = W^T tile (16 feats x 32 k, from LDS), B = X^T (32 k x 16 nodes).
// D: lane(q,m) -> node m, feats 16f+4q..+3 (consecutive -> vector stores).
// SPLIT=false (gemm1): B from fp32 X (cvt), out fp16 row-major pre-scaled:
//   Yh[node][f] = dis[node]*(X@W1)[node][f].
// SPLIT=true  (gemm2): B from fp16 Xh row-major, out fp32 mu/logstd + bias.
template <bool SPLIT>
__global__ __launch_bounds__(256) void gemm_mfma_kernel(const float* __restrict__ X,
                                                        const _Float16* __restrict__ Xh,
                                                        const _Float16* __restrict__ WT,
                                                        const float* __restrict__ dis,
                                                        const float* __restrict__ ba,
                                                        const float* __restrict__ bb,
                                                        _Float16* __restrict__ Yh,
                                                        float* __restrict__ Yf) {
  __shared__ _Float16 WL[128 * WT_S];  // 34 KB

  int t = threadIdx.x;
  // stage W^T: coalesced b128 global reads, conflict-free LDS writes
  for (int idx = t; idx < 128 * 16; idx += 256) {
    int n = idx >> 4, kk = (idx & 15) * 8;
    *(half8*)&WL[n * WT_S + kk] = *(const half8*)&WT[n * 128 + kk];
  }
  __syncthreads();

  int wid = t >> 6, lane = t & 63;
  int q = lane >> 4, m = lane & 15;
  const int ngroups = (N_NODES + 63) / 64;  // 782

  for (int g64 = blockIdx.x; g64 < ngroups; g64 += gridDim.x) {
    int node = g64 * 64 + wid * 16 + m;
    size_t nr = (size_t)min(node, N_NODES - 1);
    bool valid = node < N_NODES;

    // B fragments: lane (q,m) holds X[node][32c + 8q + j], j=0..7
    half8 xfrag[4];
    if (!SPLIT) {
#pragma unroll
      for (int c = 0; c < 4; ++c) {
        const float* ap = &X[nr * 128 + 32 * c + 8 * q];
        float4 a0 = *(const float4*)ap;
        float4 a1 = *(const float4*)(ap + 4);
        half8 af = {(_Float16)a0.x, (_Float16)a0.y, (_Float16)a0.z, (_Float16)a0.w,
                    (_Float16)a1.x, (_Float16)a1.y, (_Float16)a1.z, (_Float16)a1.w};
        xfrag[c] = af;
      }
    } else {
#pragma unroll
      for (int c = 0; c < 4; ++c) {
        xfrag[c] = *(const half8*)&Xh[nr * 128 + 32 * c + 8 * q];
      }
    }
    float dnode = SPLIT ? 0.f : dis[nr];

#pragma unroll
    for (int f = 0; f < 8; ++f) {  // feat tile: feats 16f..16f+15
      floatx4 acc = {0.f, 0.f, 0.f, 0.f};
#pragma unroll
      for (int c = 0; c < 4; ++c) {
        half8 wfrag = *(const half8*)&WL[(16 * f + m) * WT_S + 32 * c + 8 * q];
        acc = __builtin_amdgcn_mfma_f32_16x16x32_f16(wfrag, xfrag[c], acc, 0, 0, 0);
      }
      int fbase = 16 * f + 4 * q;  // 4 consecutive feats for this lane
      if (!SPLIT) {
        if (valid) {
          half4 o = {(_Float16)(acc[0] * dnode), (_Float16)(acc[1] * dnode),
                     (_Float16)(acc[2] * dnode), (_Float16)(acc[3] * dnode)};
          *(half4*)&Yh[(size_t)node * 128 + fbase] = o;
        }
      } else {
        // f<4 -> mu cols (fbase<64), f>=4 -> logstd (wave-uniform branch)
        float4 bias = (f < 4) ? *(const float4*)&ba[fbase]
                              : *(const float4*)&bb[fbase - 64];
        float4 o = make_float4(acc[0] + bias.x, acc[1] + bias.y, acc[2] + bias.z,
                               acc[3] + bias.w);
        if (valid) {
          if (f < 4)
            *(float4*)&Yf[(size_t)node * 64 + fbase] = o;
          else
            *(float4*)&Yf[MU_SIZE + (size_t)node * 64 + (fbase - 64)] = o;
        }
      }
    }
  }
}

// Padded-CSR aggregation: quarter-wave (16 lanes x float4) per node over
// pre-scaled fp16 rows. Adjacency length is a multiple of 8 -> the loop is a
// branch-free unroll-8 with 8 row-gathers (128 B/lane) in flight and NO
// serialized remainder. Pad slots read the zero row (hot 256B line).
// BIAS_RELU=true:  out[i] = fp16( di * relu(di*(sum Hs[r] + Hs[i]) + b) )
// BIAS_RELU=false: out[i] = fp16( di * (sum Hs[r] + Hs[i]) )
template <bool BIAS_RELU>
__global__ __launch_bounds__(256) void aggregate_kernel(const __half* __restrict__ Hs,
                                                        const int* __restrict__ offsets,
                                                        const int* __restrict__ srcidx,
                                                        const float* __restrict__ dis,
                                                        const float* __restrict__ bias,
                                                        __half* __restrict__ outH, int n) {
  int wid = threadIdx.x >> 6, lane = threadIdx.x & 63;
  int q = lane >> 4, ql = lane & 15;
  int i = blockIdx.x * 16 + wid * 4 + q;
  if (i >= n) return;
  float di = dis[i];
  float4 selfv = ((const float4*)(Hs + (size_t)i * 128))[ql];
  float acc[8] = {0.f, 0.f, 0.f, 0.f, 0.f, 0.f, 0.f, 0.f};
  int k = offsets[i], end = offsets[i + 1];
  for (; k < end; k += 8) {
    int r0 = srcidx[k], r1 = srcidx[k + 1], r2 = srcidx[k + 2], r3 = srcidx[k + 3];
    int r4 = srcidx[k + 4], r5 = srcidx[k + 5], r6 = srcidx[k + 6], r7 = srcidx[k + 7];
    float4 v0 = ((const float4*)(Hs + (size_t)r0 * 128))[ql];
    float4 v1 = ((const float4*)(Hs + (size_t)r1 * 128))[ql];
    float4 v2 = ((const float4*)(Hs + (size_t)r2 * 128))[ql];
    float4 v3 = ((const float4*)(Hs + (size_t)r3 * 128))[ql];
    float4 v4 = ((const float4*)(Hs + (size_t)r4 * 128))[ql];
    float4 v5 = ((const float4*)(Hs + (size_t)r5 * 128))[ql];
    float4 v6 = ((const float4*)(Hs + (size_t)r6 * 128))[ql];
    float4 v7 = ((const float4*)(Hs + (size_t)r7 * 128))[ql];
    const __half2* a0 = (const __half2*)&v0;
    const __half2* a1 = (const __half2*)&v1;
    const __half2* a2 = (const __half2*)&v2;
    const __half2* a3 = (const __half2*)&v3;
    const __half2* a4 = (const __half2*)&v4;
    const __half2* a5 = (const __half2*)&v5;
    const __half2* a6 = (const __half2*)&v6;
    const __half2* a7 = (const __half2*)&v7;
#pragma unroll
    for (int j = 0; j < 4; ++j) {
      float2 f0 = __half22float2(a0[j]);
      float2 f1 = __half22float2(a1[j]);
      float2 f2 = __half22float2(a2[j]);
      float2 f3 = __half22float2(a3[j]);
      float2 f4 = __half22float2(a4[j]);
      float2 f5 = __half22float2(a5[j]);
      float2 f6 = __half22float2(a6[j]);
      float2 f7 = __half22float2(a7[j]);
      acc[2 * j] += ((f0.x + f1.x) + (f2.x + f3.x)) + ((f4.x + f5.x) + (f6.x + f7.x));
      acc[2 * j + 1] += ((f0.y + f1.y) + (f2.y + f3.y)) + ((f4.y + f5.y) + (f6.y + f7.y));
    }
  }
  const __half2* sh = (const __half2*)&selfv;
  float2 f0 = __half22float2(sh[0]);
  float2 f1 = __half22float2(sh[1]);
  float2 f2 = __half22float2(sh[2]);
  float2 f3 = __half22float2(sh[3]);
  float s0 = di * (acc[0] + f0.x), s1 = di * (acc[1] + f0.y);
  float s2 = di * (acc[2] + f1.x), s3 = di * (acc[3] + f1.y);
  float s4 = di * (acc[4] + f2.x), s5 = di * (acc[5] + f2.y);
  float s6 = di * (acc[6] + f3.x), s7 = di * (acc[7] + f3.y);
  H8 u;
  if (BIAS_RELU) {
    float4 b0 = ((const float4*)bias)[2 * ql];
    float4 b1 = ((const float4*)bias)[2 * ql + 1];
    u.h2[0] = __float22half2_rn(
        make_float2(di * fmaxf(s0 + b0.x, 0.f), di * fmaxf(s1 + b0.y, 0.f)));
    u.h2[1] = __float22half2_rn(
        make_float2(di * fmaxf(s2 + b0.z, 0.f), di * fmaxf(s3 + b0.w, 0.f)));
    u.h2[2] = __float22half2_rn(
        make_float2(di * fmaxf(s4 + b1.x, 0.f), di * fmaxf(s5 + b1.y, 0.f)));
    u.h2[3] = __float22half2_rn(
        make_float2(di * fmaxf(s6 + b1.z, 0.f), di * fmaxf(s7 + b1.w, 0.f)));
  } else {
    u.h2[0] = __float22half2_rn(make_float2(s0, s1));
    u.h2[1] = __float22half2_rn(make_float2(s2, s3));
    u.h2[2] = __float22half2_rn(make_float2(s4, s5));
    u.h2[3] = __float22half2_rn(make_float2(s6, s7));
  }
  ((float4*)(outH + (size_t)i * 128))[ql] = u.f4;
}

extern "C" void kernel_launch(void* const* d_in, const int* in_sizes, int n_in,
                              void* d_out, int out_size, void* d_ws, size_t ws_size,
                              hipStream_t stream) {
  const float* x = (const float*)d_in[0];
  const int* ei = (const int*)d_in[1];  // [2][E] int32: row=src, col=dst
  const float* W1 = (const float*)d_in[2];
  const float* b1 = (const float*)d_in[3];
  const float* Wmu = (const float*)d_in[4];
  const float* bmu = (const float*)d_in[5];
  const float* Wls = (const float*)d_in[6];
  const float* bls = (const float*)d_in[7];
  float* out = (float*)d_out;

  const int* row = ei;
  const int* col = ei + N_EDGES;

  // workspace layout (~44 MB). bufA/bufB have an extra zero row at index N.
  __half* bufAh = (__half*)d_ws;               // 6400128 f16 (gemm1 out, agg1 in)
  __half* bufBh = bufAh + 6400128;             // 6400128 f16 (agg1 out, agg2 in)
  __half* bufCh = bufBh + 6400128;             // 6400000 f16 (agg2 out, gemm2 in)
  float* dis = (float*)(bufCh + 6400000);      // 50000 f32
  int* counts = (int*)(dis + N_NODES);         // 50000 i32
  int* fillcnt = counts + N_NODES;             // 50000 i32 (contiguous after counts)
  int* offsets = fillcnt + N_NODES;            // 50001 i32
  int* srcidx = offsets + N_NODES + 1;         // 960000 i32 (padded CSR)
  int* blocksums = srcidx + PAD_CAP;           // 200 i32
  _Float16* W1T = (_Float16*)(blocksums + 256);  // 16384 f16
  _Float16* W2T = W1T + 16384;                   // 16384 f16

  prep_kernel<<<128, 256, 0, stream>>>(W1, Wmu, Wls, W1T, W2T, counts, srcidx,
                                       bufAh + (size_t)N_NODES * 128,
                                       bufBh + (size_t)N_NODES * 128);

  int eb = (N_EDGES + 255) / 256;
  count_kernel<<<eb, 256, 0, stream>>>(col, counts, N_EDGES);
  blocksum_dis_kernel<<<SCAN_BLOCKS, 256, 0, stream>>>(counts, dis, blocksums);
  offsets_kernel<<<SCAN_BLOCKS, 256, 0, stream>>>(counts, blocksums, offsets);
  fill_kernel<<<eb, 256, 0, stream>>>(row, col, offsets, fillcnt, srcidx, N_EDGES);

  gemm_mfma_kernel<false><<<512, 256, 0, stream>>>(x, nullptr, W1T, dis, nullptr, nullptr,
                                                   (_Float16*)bufAh, nullptr);
  int ab = (N_NODES + 15) / 16;  // 3125
  aggregate_kernel<true><<<ab, 256, 0, stream>>>(bufAh, offsets, srcidx, dis, b1,
                                                 bufBh, N_NODES);
  aggregate_kernel<false><<<ab, 256, 0, stream>>>(bufBh, offsets, srcidx, dis,
                                                  nullptr, bufCh, N_NODES);
  gemm_mfma_kernel<true><<<512, 256, 0, stream>>>(nullptr, (const _Float16*)bufCh, W2T,
                                                  nullptr, bmu, bls, nullptr, out);
}